// Round 1
// baseline (238.920 us; speedup 1.0000x reference)
//
#include <hip/hip_runtime.h>
#include <hip/hip_bf16.h>
#include <math.h>

typedef __attribute__((ext_vector_type(8))) short bf16x8;
typedef __attribute__((ext_vector_type(4))) float f32x4;

#define B_ 8
#define S_ 1024
#define E_ 128
#define H_ 16
#define M_ (B_*S_)
#define F_ (3*H_*E_)

__device__ __forceinline__ unsigned short f2b(float x) {
  __hip_bfloat16 h = __float2bfloat16(x);
  return *reinterpret_cast<unsigned short*>(&h);
}

__device__ __forceinline__ f32x4 mfma16(bf16x8 a, bf16x8 b, f32x4 c) {
  return __builtin_amdgcn_mfma_f32_16x16x32_bf16(a, b, c, 0, 0, 0);
}

// ---------------- prep: fp32->bf16 + rope tables ----------------
__global__ __launch_bounds__(256) void prep_kernel(
    const float* __restrict__ seq, const float* __restrict__ wq,
    unsigned short* __restrict__ seqb, unsigned short* __restrict__ wb,
    float* __restrict__ ctab, float* __restrict__ stab)
{
  int i = blockIdx.x * 256 + threadIdx.x;   // grid = 1024 blocks -> 262144 threads
  if (i < M_*E_/4) {
    float4 v = reinterpret_cast<const float4*>(seq)[i];
    ushort4 o; o.x = f2b(v.x); o.y = f2b(v.y); o.z = f2b(v.z); o.w = f2b(v.w);
    reinterpret_cast<ushort4*>(seqb)[i] = o;
  }
  if (i < F_*E_/4) {
    float4 v = reinterpret_cast<const float4*>(wq)[i];
    ushort4 o; o.x = f2b(v.x); o.y = f2b(v.y); o.z = f2b(v.z); o.w = f2b(v.w);
    reinterpret_cast<ushort4*>(wb)[i] = o;
  }
  if (i < S_*64) {
    int s = i >> 6, e = i & 63;
    double ang = (double)s * pow(10000.0, -(double)e / 64.0);
    ctab[i] = (float)cos(ang);
    stab[i] = (float)sin(ang);
  }
}

// ---------------- QKV GEMM + bias + rope, writes Q,K (B,H,S,E) and V^T (B,H,E,S) ----------------
__global__ __launch_bounds__(256) void qkv_gemm_kernel(
    const unsigned short* __restrict__ Ab, const unsigned short* __restrict__ Wb,
    const float* __restrict__ bias, const float* __restrict__ ctab, const float* __restrict__ stab,
    unsigned short* __restrict__ qo, unsigned short* __restrict__ ko, unsigned short* __restrict__ vt)
{
  __shared__ unsigned short As[128][136];   // +8 pad: b128 reads hit bank-quad minimum
  __shared__ unsigned short Ws[128][136];
  const int bm = blockIdx.x, bn = blockIdx.y;
  const int t = threadIdx.x;
  const int w = t >> 6, l = t & 63, lc = l & 15, g = l >> 4;

  #pragma unroll
  for (int i = 0; i < 8; ++i) {
    int c = t + i * 256, row = c >> 4, kc = c & 15;
    *reinterpret_cast<bf16x8*>(&As[row][kc*8]) =
        *reinterpret_cast<const bf16x8*>(&Ab[(size_t)(bm*128+row)*128 + kc*8]);
    *reinterpret_cast<bf16x8*>(&Ws[row][kc*8]) =
        *reinterpret_cast<const bf16x8*>(&Wb[(size_t)(bn*128+row)*128 + kc*8]);
  }
  __syncthreads();

  const f32x4 zero = {0.f, 0.f, 0.f, 0.f};
  f32x4 acc[2][8];
  #pragma unroll
  for (int mi=0;mi<2;mi++)
    #pragma unroll
    for (int nj=0;nj<8;nj++) acc[mi][nj] = zero;

  #pragma unroll
  for (int ks = 0; ks < 4; ++ks) {
    bf16x8 a[2], b[8];
    #pragma unroll
    for (int mi=0;mi<2;mi++)
      a[mi] = *reinterpret_cast<const bf16x8*>(&As[w*32 + mi*16 + lc][ks*32 + g*8]);
    #pragma unroll
    for (int nj=0;nj<8;nj++)
      b[nj] = *reinterpret_cast<const bf16x8*>(&Ws[nj*16 + lc][ks*32 + g*8]);
    #pragma unroll
    for (int mi=0;mi<2;mi++)
      #pragma unroll
      for (int nj=0;nj<8;nj++)
        acc[mi][nj] = mfma16(a[mi], b[nj], acc[mi][nj]);
  }

  float bv[8];
  #pragma unroll
  for (int nj=0;nj<8;nj++) bv[nj] = bias[bn*128 + nj*16 + lc];

  const int c3 = bn >> 4, h = bn & 15;
  if (c3 < 2) {
    unsigned short* dst = (c3 == 0) ? qo : ko;
    const float mul = (c3 == 1) ? 0.08838834764831845f : 1.0f;  // fold 1/sqrt(128) into K
    #pragma unroll
    for (int mi=0;mi<2;mi++)
      #pragma unroll
      for (int r=0;r<4;r++) {
        int mrow = bm*128 + w*32 + mi*16 + g*4 + r;
        int bb = mrow >> 10, s = mrow & 1023;
        size_t ob = ((size_t)(bb*H_ + h)*S_ + s)*E_;
        #pragma unroll
        for (int nj=0;nj<4;nj++) {
          int e1 = nj*16 + lc;
          float x1 = acc[mi][nj][r]   + bv[nj];
          float x2 = acc[mi][nj+4][r] + bv[nj+4];
          float cs = ctab[s*64 + e1], sn = stab[s*64 + e1];
          dst[ob + e1]      = f2b((x1*cs - x2*sn) * mul);
          dst[ob + e1 + 64] = f2b((x1*sn + x2*cs) * mul);
        }
      }
  } else {
    // V: bias only; transpose in LDS so attention can read (d, kv) row-major
    __syncthreads();
    #pragma unroll
    for (int mi=0;mi<2;mi++)
      #pragma unroll
      for (int nj=0;nj<8;nj++)
        #pragma unroll
        for (int r=0;r<4;r++)
          As[nj*16 + lc][w*32 + mi*16 + g*4 + r] = f2b(acc[mi][nj][r] + bv[nj]);
    __syncthreads();
    int bb = bm >> 3, sb = (bm & 7) * 128;
    #pragma unroll
    for (int i=0;i<8;i++) {
      int cidx = t + i*256, e = cidx >> 4, sc = cidx & 15;
      *reinterpret_cast<bf16x8*>(&vt[((size_t)(bb*H_ + h)*E_ + e)*S_ + sb + sc*8]) =
          *reinterpret_cast<const bf16x8*>(&As[e][sc*8]);
    }
  }
}

// ---------------- flash attention: 4 waves x 32 q-rows, KV tile = 64 ----------------
__global__ __launch_bounds__(256) void attn_kernel(
    const unsigned short* __restrict__ qg, const unsigned short* __restrict__ kg,
    const unsigned short* __restrict__ vtg, float* __restrict__ out)
{
  __shared__ unsigned short Ks[64][136];
  __shared__ unsigned short Vs[128][72];
  __shared__ unsigned short Ps[4][32][72];
  const int bh = blockIdx.x, qb = blockIdx.y;
  const int t = threadIdx.x, w = t >> 6, l = t & 63, lc = l & 15, g = l >> 4;
  const size_t base = (size_t)bh * S_ * E_;

  // Q tile in registers: wave w owns q rows qb*128 + w*32 .. +31
  bf16x8 qreg[2][4];
  #pragma unroll
  for (int mi=0;mi<2;mi++)
    #pragma unroll
    for (int ks=0;ks<4;ks++)
      qreg[mi][ks] = *reinterpret_cast<const bf16x8*>(
          &qg[base + (size_t)(qb*128 + w*32 + mi*16 + lc)*E_ + ks*32 + g*8]);

  const f32x4 zero = {0.f, 0.f, 0.f, 0.f};
  f32x4 acc_o[2][8];
  float m_run[2][4], l_run[2][4];
  #pragma unroll
  for (int mi=0;mi<2;mi++) {
    #pragma unroll
    for (int nd=0;nd<8;nd++) acc_o[mi][nd] = zero;
    #pragma unroll
    for (int r=0;r<4;r++) { m_run[mi][r] = -1e30f; l_run[mi][r] = 0.f; }
  }

  for (int kt = 0; kt < 16; ++kt) {
    __syncthreads();   // all waves done reading previous K/V tile
    #pragma unroll
    for (int i=0;i<4;i++) {
      int cidx = t + i*256, row = cidx >> 4, kc = cidx & 15;
      *reinterpret_cast<bf16x8*>(&Ks[row][kc*8]) =
          *reinterpret_cast<const bf16x8*>(&kg[base + (size_t)(kt*64 + row)*E_ + kc*8]);
    }
    #pragma unroll
    for (int i=0;i<4;i++) {
      int cidx = t + i*256, e = cidx >> 3, sc = cidx & 7;
      *reinterpret_cast<bf16x8*>(&Vs[e][sc*8]) =
          *reinterpret_cast<const bf16x8*>(&vtg[base + (size_t)e*S_ + kt*64 + sc*8]);
    }
    __syncthreads();

    // S = Q K^T (K pre-scaled by 1/sqrt(D))
    f32x4 sa[2][4];
    #pragma unroll
    for (int mi=0;mi<2;mi++)
      #pragma unroll
      for (int nj=0;nj<4;nj++) sa[mi][nj] = zero;
    #pragma unroll
    for (int ks=0;ks<4;ks++) {
      bf16x8 bfr[4];
      #pragma unroll
      for (int nj=0;nj<4;nj++)
        bfr[nj] = *reinterpret_cast<const bf16x8*>(&Ks[nj*16 + lc][ks*32 + g*8]);
      #pragma unroll
      for (int mi=0;mi<2;mi++)
        #pragma unroll
        for (int nj=0;nj<4;nj++)
          sa[mi][nj] = mfma16(qreg[mi][ks], bfr[nj], sa[mi][nj]);
    }

    // online softmax: row q = g*4+r, cols spread over 16 lanes (lc) x 4 frags
    #pragma unroll
    for (int mi=0;mi<2;mi++)
      #pragma unroll
      for (int r=0;r<4;r++) {
        float mx = fmaxf(fmaxf(sa[mi][0][r], sa[mi][1][r]), fmaxf(sa[mi][2][r], sa[mi][3][r]));
        #pragma unroll
        for (int off=1; off<16; off<<=1) mx = fmaxf(mx, __shfl_xor(mx, off, 64));
        float mn = fmaxf(m_run[mi][r], mx);
        float alpha = __expf(m_run[mi][r] - mn);
        float rs = 0.f;
        #pragma unroll
        for (int nj=0;nj<4;nj++) {
          float p = __expf(sa[mi][nj][r] - mn);
          sa[mi][nj][r] = p;
          rs += p;
        }
        #pragma unroll
        for (int off=1; off<16; off<<=1) rs += __shfl_xor(rs, off, 64);
        m_run[mi][r] = mn;
        l_run[mi][r] = l_run[mi][r]*alpha + rs;
        #pragma unroll
        for (int nd=0;nd<8;nd++) acc_o[mi][nd][r] *= alpha;
      }

    // P -> bf16 -> per-wave LDS (no cross-wave hazard, no barrier)
    #pragma unroll
    for (int mi=0;mi<2;mi++)
      #pragma unroll
      for (int nj=0;nj<4;nj++)
        #pragma unroll
        for (int r=0;r<4;r++)
          Ps[w][mi*16 + g*4 + r][nj*16 + lc] = f2b(sa[mi][nj][r]);

    // O += P V  (Vs is V^T: rows=d, k=kv)
    #pragma unroll
    for (int ks=0;ks<2;ks++) {
      bf16x8 pa[2];
      #pragma unroll
      for (int mi=0;mi<2;mi++)
        pa[mi] = *reinterpret_cast<const bf16x8*>(&Ps[w][mi*16 + lc][ks*32 + g*8]);
      #pragma unroll
      for (int nd=0;nd<8;nd++) {
        bf16x8 bvv = *reinterpret_cast<const bf16x8*>(&Vs[nd*16 + lc][ks*32 + g*8]);
        #pragma unroll
        for (int mi=0;mi<2;mi++)
          acc_o[mi][nd] = mfma16(pa[mi], bvv, acc_o[mi][nd]);
      }
    }
  }

  // epilogue: out (B,S,H,E) fp32
  const int bb = bh >> 4, h = bh & 15;
  #pragma unroll
  for (int mi=0;mi<2;mi++)
    #pragma unroll
    for (int r=0;r<4;r++) {
      int s = qb*128 + w*32 + mi*16 + g*4 + r;
      float inv = 1.0f / l_run[mi][r];
      size_t ob = ((size_t)(bb*S_ + s)*H_ + h)*E_;
      #pragma unroll
      for (int nd=0;nd<8;nd++)
        out[ob + nd*16 + lc] = acc_o[mi][nd][r] * inv;
    }
}

extern "C" void kernel_launch(void* const* d_in, const int* in_sizes, int n_in,
                              void* d_out, int out_size, void* d_ws, size_t ws_size,
                              hipStream_t stream) {
  const float* seq = (const float*)d_in[0];
  const float* wq  = (const float*)d_in[1];
  const float* bq  = (const float*)d_in[2];
  float* out = (float*)d_out;
  char* ws = (char*)d_ws;
  size_t off = 0;
  unsigned short* seqb = (unsigned short*)(ws + off); off += (size_t)M_*E_*2;     // 2 MB
  unsigned short* wb   = (unsigned short*)(ws + off); off += (size_t)F_*E_*2;     // 1.5 MB
  float* ctab = (float*)(ws + off); off += (size_t)S_*64*4;                       // 256 KB
  float* stab = (float*)(ws + off); off += (size_t)S_*64*4;                       // 256 KB
  unsigned short* qbuf = (unsigned short*)(ws + off); off += (size_t)B_*H_*S_*E_*2; // 32 MB
  unsigned short* kbuf = (unsigned short*)(ws + off); off += (size_t)B_*H_*S_*E_*2; // 32 MB
  unsigned short* vtbuf= (unsigned short*)(ws + off); off += (size_t)B_*H_*S_*E_*2; // 32 MB

  prep_kernel<<<dim3(1024), dim3(256), 0, stream>>>(seq, wq, seqb, wb, ctab, stab);
  qkv_gemm_kernel<<<dim3(64, 48), dim3(256), 0, stream>>>(seqb, wb, bq, ctab, stab, qbuf, kbuf, vtbuf);
  attn_kernel<<<dim3(128, 8), dim3(256), 0, stream>>>(qbuf, kbuf, vtbuf, out);
}

// Round 2
// 173.939 us; speedup vs baseline: 1.3736x; 1.3736x over previous
//
#include <hip/hip_runtime.h>
#include <hip/hip_bf16.h>
#include <math.h>

typedef __attribute__((ext_vector_type(8))) short bf16x8;
typedef __attribute__((ext_vector_type(4))) float f32x4;
typedef __attribute__((ext_vector_type(16))) float f32x16;

#define B_ 8
#define S_ 1024
#define E_ 128
#define H_ 16
#define M_ (B_*S_)
#define F_ (3*H_*E_)

__device__ __forceinline__ unsigned short f2b(float x) {
  __hip_bfloat16 h = __float2bfloat16(x);
  return *reinterpret_cast<unsigned short*>(&h);
}

__device__ __forceinline__ f32x4 mfma16(bf16x8 a, bf16x8 b, f32x4 c) {
  return __builtin_amdgcn_mfma_f32_16x16x32_bf16(a, b, c, 0, 0, 0);
}
__device__ __forceinline__ f32x16 mfma32(bf16x8 a, bf16x8 b, f32x16 c) {
  return __builtin_amdgcn_mfma_f32_32x32x16_bf16(a, b, c, 0, 0, 0);
}
__device__ __forceinline__ unsigned cvtpk(float a, float b) {
  unsigned r; asm("v_cvt_pk_bf16_f32 %0, %1, %2" : "=v"(r) : "v"(a), "v"(b)); return r;
}

// ---------------- prep: fp32->bf16 + rope tables ----------------
__global__ __launch_bounds__(256) void prep_kernel(
    const float* __restrict__ seq, const float* __restrict__ wq,
    unsigned short* __restrict__ seqb, unsigned short* __restrict__ wb,
    float* __restrict__ ctab, float* __restrict__ stab)
{
  int i = blockIdx.x * 256 + threadIdx.x;
  if (i < M_*E_/4) {
    float4 v = reinterpret_cast<const float4*>(seq)[i];
    ushort4 o; o.x = f2b(v.x); o.y = f2b(v.y); o.z = f2b(v.z); o.w = f2b(v.w);
    reinterpret_cast<ushort4*>(seqb)[i] = o;
  }
  if (i < F_*E_/4) {
    float4 v = reinterpret_cast<const float4*>(wq)[i];
    ushort4 o; o.x = f2b(v.x); o.y = f2b(v.y); o.z = f2b(v.z); o.w = f2b(v.w);
    reinterpret_cast<ushort4*>(wb)[i] = o;
  }
  if (i < S_*64) {
    int s = i >> 6, e = i & 63;
    double ang = (double)s * pow(10000.0, -(double)e / 64.0);
    ctab[i] = (float)cos(ang);
    stab[i] = (float)sin(ang);
  }
}

// ---------------- QKV GEMM + bias + rope -> Q,K (B,H,S,E), V^T (B,H,E,S) ----------------
// K is pre-scaled by (1/sqrt(128)) * log2(e) so attention can use exp2 directly.
__global__ __launch_bounds__(256) void qkv_gemm_kernel(
    const unsigned short* __restrict__ Ab, const unsigned short* __restrict__ Wb,
    const float* __restrict__ bias, const float* __restrict__ ctab, const float* __restrict__ stab,
    unsigned short* __restrict__ qo, unsigned short* __restrict__ ko, unsigned short* __restrict__ vt)
{
  __shared__ unsigned short As[128][136];
  __shared__ unsigned short Ws[128][136];
  const int bm = blockIdx.x, bn = blockIdx.y;
  const int t = threadIdx.x;
  const int w = t >> 6, l = t & 63, lc = l & 15, g = l >> 4;

  #pragma unroll
  for (int i = 0; i < 8; ++i) {
    int c = t + i * 256, row = c >> 4, kc = c & 15;
    *reinterpret_cast<bf16x8*>(&As[row][kc*8]) =
        *reinterpret_cast<const bf16x8*>(&Ab[(size_t)(bm*128+row)*128 + kc*8]);
    *reinterpret_cast<bf16x8*>(&Ws[row][kc*8]) =
        *reinterpret_cast<const bf16x8*>(&Wb[(size_t)(bn*128+row)*128 + kc*8]);
  }
  __syncthreads();

  const f32x4 zero = {0.f, 0.f, 0.f, 0.f};
  f32x4 acc[2][8];
  #pragma unroll
  for (int mi=0;mi<2;mi++)
    #pragma unroll
    for (int nj=0;nj<8;nj++) acc[mi][nj] = zero;

  #pragma unroll
  for (int ks = 0; ks < 4; ++ks) {
    bf16x8 a[2], b[8];
    #pragma unroll
    for (int mi=0;mi<2;mi++)
      a[mi] = *reinterpret_cast<const bf16x8*>(&As[w*32 + mi*16 + lc][ks*32 + g*8]);
    #pragma unroll
    for (int nj=0;nj<8;nj++)
      b[nj] = *reinterpret_cast<const bf16x8*>(&Ws[nj*16 + lc][ks*32 + g*8]);
    #pragma unroll
    for (int mi=0;mi<2;mi++)
      #pragma unroll
      for (int nj=0;nj<8;nj++)
        acc[mi][nj] = mfma16(a[mi], b[nj], acc[mi][nj]);
  }

  float bv[8];
  #pragma unroll
  for (int nj=0;nj<8;nj++) bv[nj] = bias[bn*128 + nj*16 + lc];

  const int c3 = bn >> 4, h = bn & 15;
  if (c3 < 2) {
    unsigned short* dst = (c3 == 0) ? qo : ko;
    const float mul = (c3 == 1) ? 0.12751742f : 1.0f;  // (1/sqrt(128))*log2e folded into K
    #pragma unroll
    for (int mi=0;mi<2;mi++)
      #pragma unroll
      for (int r=0;r<4;r++) {
        int mrow = bm*128 + w*32 + mi*16 + g*4 + r;
        int bb = mrow >> 10, s = mrow & 1023;
        size_t ob = ((size_t)(bb*H_ + h)*S_ + s)*E_;
        #pragma unroll
        for (int nj=0;nj<4;nj++) {
          int e1 = nj*16 + lc;
          float x1 = acc[mi][nj][r]   + bv[nj];
          float x2 = acc[mi][nj+4][r] + bv[nj+4];
          float cs = ctab[s*64 + e1], sn = stab[s*64 + e1];
          dst[ob + e1]      = f2b((x1*cs - x2*sn) * mul);
          dst[ob + e1 + 64] = f2b((x1*sn + x2*cs) * mul);
        }
      }
  } else {
    __syncthreads();
    #pragma unroll
    for (int mi=0;mi<2;mi++)
      #pragma unroll
      for (int nj=0;nj<8;nj++)
        #pragma unroll
        for (int r=0;r<4;r++)
          As[nj*16 + lc][w*32 + mi*16 + g*4 + r] = f2b(acc[mi][nj][r] + bv[nj]);
    __syncthreads();
    int bb = bm >> 3, sb = (bm & 7) * 128;
    #pragma unroll
    for (int i=0;i<8;i++) {
      int cidx = t + i*256, e = cidx >> 4, sc = cidx & 15;
      *reinterpret_cast<bf16x8*>(&vt[((size_t)(bb*H_ + h)*E_ + e)*S_ + sb + sc*8]) =
          *reinterpret_cast<const bf16x8*>(&As[e][sc*8]);
    }
  }
}

// ---------------- flash attention: 4 waves x 32 q-rows, 32x32 MFMA, swapped QK^T ----------------
__global__ __launch_bounds__(256) void attn_kernel(
    const unsigned short* __restrict__ qg, const unsigned short* __restrict__ kg,
    const unsigned short* __restrict__ vtg, float* __restrict__ out)
{
  // K tile: [64 rows][128 cols] bf16, 16B-block-swizzled: blk ^= row&15
  // V^T tile: [128 d-rows][64 cols] bf16, blk ^= row&7
  __shared__ unsigned short Ks[2][64*128];
  __shared__ unsigned short Vs[2][128*64];
  const int bh = blockIdx.x, qb = blockIdx.y;
  const int t = threadIdx.x, w = t >> 6, l = t & 63;
  const int q32 = l & 31, hi = l >> 5;
  const size_t base = (size_t)bh * (S_*E_);
  const int bb = bh >> 4, h = bh & 15;

  // Q in registers: B-operand layout (row = q32, k-chunk = hi*8 within each 16-d window)
  bf16x8 qreg[8];
  {
    const unsigned short* qrow = qg + base + (size_t)(qb*128 + w*32 + q32)*E_;
    #pragma unroll
    for (int dc=0;dc<8;dc++)
      qreg[dc] = *reinterpret_cast<const bf16x8*>(qrow + dc*16 + hi*8);
  }

  // pre-swizzled global source addresses for global_load_lds staging
  const char* ksrc[4]; const char* vsrc[4];
  #pragma unroll
  for (int i=0;i<4;i++) {
    int r  = w*16 + i*4 + (l>>4);
    int cb = (l&15) ^ (r&15);
    ksrc[i] = (const char*)(kg + base + (size_t)r*E_ + cb*8);
    int rd  = w*32 + i*8 + (l>>3);
    int vb  = (l&7) ^ (rd&7);
    vsrc[i] = (const char*)(vtg + base + (size_t)rd*S_ + vb*8);
  }

  auto stage = [&](int bufi, int tt) {
    const size_t koff = (size_t)tt * (64*E_) * 2;   // bytes
    const size_t voff = (size_t)tt * 64 * 2;        // bytes
    #pragma unroll
    for (int i=0;i<4;i++)
      __builtin_amdgcn_global_load_lds(
        (const __attribute__((address_space(1))) void*)(ksrc[i] + koff),
        (__attribute__((address_space(3))) void*)(&Ks[bufi][(w*16 + i*4)*128]),
        16, 0, 0);
    #pragma unroll
    for (int i=0;i<4;i++)
      __builtin_amdgcn_global_load_lds(
        (const __attribute__((address_space(1))) void*)(vsrc[i] + voff),
        (__attribute__((address_space(3))) void*)(&Vs[bufi][(w*32 + i*8)*64]),
        16, 0, 0);
  };

  const f32x16 z16 = {0,0,0,0,0,0,0,0,0,0,0,0,0,0,0,0};
  f32x16 accO[4];
  #pragma unroll
  for (int dc=0;dc<4;dc++) accO[dc] = z16;
  float m_run = -1e30f, lsum = 0.f;

  stage(0, 0);
  __syncthreads();

  for (int tt = 0; tt < 16; ++tt) {
    const int cur = tt & 1;
    if (tt < 15) stage(cur ^ 1, tt + 1);

    // S^T = K Q^T : C[k][q], lane col q = q32, rows k = crow(reg,hi)
    f32x16 s0 = z16, s1 = z16;
    #pragma unroll
    for (int dc=0; dc<8; dc++) {
      int blk = ((dc*2 + hi) ^ (q32 & 15)) * 8;
      bf16x8 k0 = *reinterpret_cast<const bf16x8*>(&Ks[cur][(q32)*128 + blk]);
      bf16x8 k1 = *reinterpret_cast<const bf16x8*>(&Ks[cur][(32 + q32)*128 + blk]);
      s0 = mfma32(k0, qreg[dc], s0);
      s1 = mfma32(k1, qreg[dc], s1);
    }

    // row max: in-lane tree over 32 + cross-hi
    float tv[8];
    #pragma unroll
    for (int j=0;j<8;j++) tv[j] = fmaxf(fmaxf(s0[j], s0[j+8]), fmaxf(s1[j], s1[j+8]));
    #pragma unroll
    for (int st=4; st>0; st>>=1)
      #pragma unroll
      for (int j=0;j<st;j++) tv[j] = fmaxf(tv[j], tv[j+st]);
    float tmax = fmaxf(tv[0], __shfl_xor(tv[0], 32));

    // defer-max rescale (THR = 8 ln-units = 11.54 log2-units)
    if (!__all(tmax <= m_run + 11.54f)) {
      float mn = fmaxf(m_run, tmax);
      float al = __builtin_amdgcn_exp2f(m_run - mn);
      m_run = mn; lsum *= al;
      #pragma unroll
      for (int dc=0;dc<4;dc++)
        #pragma unroll
        for (int j=0;j<16;j++) accO[dc][j] *= al;
    }

    // P = exp2(S - m), per-lane partial row-sum (cross-hi reduce deferred to epilogue)
    #pragma unroll
    for (int j=0;j<16;j++) {
      s0[j] = __builtin_amdgcn_exp2f(s0[j] - m_run);
      s1[j] = __builtin_amdgcn_exp2f(s1[j] - m_run);
    }
    float sv2[8];
    #pragma unroll
    for (int j=0;j<8;j++) sv2[j] = (s0[j]+s0[j+8]) + (s1[j]+s1[j+8]);
    #pragma unroll
    for (int st=4; st>0; st>>=1)
      #pragma unroll
      for (int j=0;j<st;j++) sv2[j] += sv2[j+st];
    lsum += sv2[0];

    // in-register P->bf16 repack to B-operand layout, then O^T += V^T P^T
    #pragma unroll
    for (int kt=0; kt<2; ++kt) {
      const f32x16 sv = kt ? s1 : s0;
      #pragma unroll
      for (int c=0; c<2; ++c) {
        unsigned c01 = cvtpk(sv[8*c+0], sv[8*c+1]);
        unsigned c23 = cvtpk(sv[8*c+2], sv[8*c+3]);
        unsigned c45 = cvtpk(sv[8*c+4], sv[8*c+5]);
        unsigned c67 = cvtpk(sv[8*c+6], sv[8*c+7]);
        unsigned ta = hi ? c01 : c45;  ta = __shfl_xor(ta, 32);
        unsigned tb = hi ? c23 : c67;  tb = __shfl_xor(tb, 32);
        union { unsigned u[4]; bf16x8 v; } pu;
        pu.u[0] = hi ? ta : c01;
        pu.u[1] = hi ? tb : c23;
        pu.u[2] = hi ? c45 : ta;
        pu.u[3] = hi ? c67 : tb;
        #pragma unroll
        for (int dc=0;dc<4;dc++) {
          bf16x8 vf = *reinterpret_cast<const bf16x8*>(
              &Vs[cur][(dc*32 + q32)*64 + (((kt*4 + c*2 + hi) ^ (q32 & 7)) * 8)]);
          accO[dc] = mfma32(vf, pu.v, accO[dc]);
        }
      }
    }
    __syncthreads();   // drains stage(t+1) vmcnt + protects buffer swap
  }

  // epilogue: cross-hi l reduction; C[d][q] -> out (B,S,H,E), float4 stores
  float lt = lsum + __shfl_xor(lsum, 32);
  float inv = 1.0f / lt;
  const int s = qb*128 + w*32 + q32;
  float* orow = out + ((size_t)(bb*S_ + s)*H_ + h)*E_;
  #pragma unroll
  for (int dc=0;dc<4;dc++)
    #pragma unroll
    for (int rq=0;rq<4;rq++) {
      float4 o4;
      o4.x = accO[dc][rq*4+0]*inv;
      o4.y = accO[dc][rq*4+1]*inv;
      o4.z = accO[dc][rq*4+2]*inv;
      o4.w = accO[dc][rq*4+3]*inv;
      *reinterpret_cast<float4*>(orow + dc*32 + rq*8 + hi*4) = o4;
    }
}

extern "C" void kernel_launch(void* const* d_in, const int* in_sizes, int n_in,
                              void* d_out, int out_size, void* d_ws, size_t ws_size,
                              hipStream_t stream) {
  const float* seq = (const float*)d_in[0];
  const float* wq  = (const float*)d_in[1];
  const float* bq  = (const float*)d_in[2];
  float* out = (float*)d_out;
  char* ws = (char*)d_ws;
  size_t off = 0;
  unsigned short* seqb = (unsigned short*)(ws + off); off += (size_t)M_*E_*2;
  unsigned short* wb   = (unsigned short*)(ws + off); off += (size_t)F_*E_*2;
  float* ctab = (float*)(ws + off); off += (size_t)S_*64*4;
  float* stab = (float*)(ws + off); off += (size_t)S_*64*4;
  unsigned short* qbuf = (unsigned short*)(ws + off); off += (size_t)B_*H_*S_*E_*2;
  unsigned short* kbuf = (unsigned short*)(ws + off); off += (size_t)B_*H_*S_*E_*2;
  unsigned short* vtbuf= (unsigned short*)(ws + off); off += (size_t)B_*H_*S_*E_*2;

  prep_kernel<<<dim3(1024), dim3(256), 0, stream>>>(seq, wq, seqb, wb, ctab, stab);
  qkv_gemm_kernel<<<dim3(64, 48), dim3(256), 0, stream>>>(seqb, wb, bq, ctab, stab, qbuf, kbuf, vtbuf);
  attn_kernel<<<dim3(128, 8), dim3(256), 0, stream>>>(qbuf, kbuf, vtbuf, out);
}

// Round 4
// 141.184 us; speedup vs baseline: 1.6923x; 1.2320x over previous
//
#include <hip/hip_runtime.h>
#include <hip/hip_bf16.h>
#include <math.h>

typedef __attribute__((ext_vector_type(8))) short bf16x8;
typedef __attribute__((ext_vector_type(4))) float f32x4;
typedef __attribute__((ext_vector_type(16))) float f32x16;

#define B_ 8
#define S_ 1024
#define E_ 128
#define H_ 16
#define M_ (B_*S_)
#define F_ (3*H_*E_)

__device__ __forceinline__ unsigned short f2b(float x) {
  __hip_bfloat16 h = __float2bfloat16(x);
  return *reinterpret_cast<unsigned short*>(&h);
}

__device__ __forceinline__ f32x4 mfma16(bf16x8 a, bf16x8 b, f32x4 c) {
  return __builtin_amdgcn_mfma_f32_16x16x32_bf16(a, b, c, 0, 0, 0);
}
__device__ __forceinline__ f32x16 mfma32(bf16x8 a, bf16x8 b, f32x16 c) {
  return __builtin_amdgcn_mfma_f32_32x32x16_bf16(a, b, c, 0, 0, 0);
}
__device__ __forceinline__ unsigned cvtpk(float a, float b) {
  unsigned r; asm("v_cvt_pk_bf16_f32 %0, %1, %2" : "=v"(r) : "v"(a), "v"(b)); return r;
}

// ---------------- prep: fp32->bf16 + rope tables ----------------
__global__ __launch_bounds__(256) void prep_kernel(
    const float* __restrict__ seq, const float* __restrict__ wq,
    unsigned short* __restrict__ seqb, unsigned short* __restrict__ wb,
    float* __restrict__ ctab, float* __restrict__ stab)
{
  int i = blockIdx.x * 256 + threadIdx.x;
  if (i < M_*E_/4) {
    float4 v = reinterpret_cast<const float4*>(seq)[i];
    ushort4 o; o.x = f2b(v.x); o.y = f2b(v.y); o.z = f2b(v.z); o.w = f2b(v.w);
    reinterpret_cast<ushort4*>(seqb)[i] = o;
  }
  if (i < F_*E_/4) {
    float4 v = reinterpret_cast<const float4*>(wq)[i];
    ushort4 o; o.x = f2b(v.x); o.y = f2b(v.y); o.z = f2b(v.z); o.w = f2b(v.w);
    reinterpret_cast<ushort4*>(wb)[i] = o;
  }
  if (i < S_*64) {
    int s = i >> 6, e = i & 63;
    double ang = (double)s * pow(10000.0, -(double)e / 64.0);
    ctab[i] = (float)cos(ang);
    stab[i] = (float)sin(ang);
  }
}

// ---------------- QKV GEMM + bias + rope -> Q,K (B,H,S,E), V^T (B,H,E,S) ----------------
// K pre-scaled by (1/sqrt(128)) * log2(e) so attention uses exp2 directly.
__global__ __launch_bounds__(256) void qkv_gemm_kernel(
    const unsigned short* __restrict__ Ab, const unsigned short* __restrict__ Wb,
    const float* __restrict__ bias, const float* __restrict__ ctab, const float* __restrict__ stab,
    unsigned short* __restrict__ qo, unsigned short* __restrict__ ko, unsigned short* __restrict__ vt)
{
  __shared__ unsigned short As[128][136];
  __shared__ unsigned short Ws[128][136];
  const int bm = blockIdx.x, bn = blockIdx.y;
  const int t = threadIdx.x;
  const int w = t >> 6, l = t & 63, lc = l & 15, g = l >> 4;

  #pragma unroll
  for (int i = 0; i < 8; ++i) {
    int c = t + i * 256, row = c >> 4, kc = c & 15;
    *reinterpret_cast<bf16x8*>(&As[row][kc*8]) =
        *reinterpret_cast<const bf16x8*>(&Ab[(size_t)(bm*128+row)*128 + kc*8]);
    *reinterpret_cast<bf16x8*>(&Ws[row][kc*8]) =
        *reinterpret_cast<const bf16x8*>(&Wb[(size_t)(bn*128+row)*128 + kc*8]);
  }
  __syncthreads();

  const f32x4 zero = {0.f, 0.f, 0.f, 0.f};
  f32x4 acc[2][8];
  #pragma unroll
  for (int mi=0;mi<2;mi++)
    #pragma unroll
    for (int nj=0;nj<8;nj++) acc[mi][nj] = zero;

  #pragma unroll
  for (int ks = 0; ks < 4; ++ks) {
    bf16x8 a[2], b[8];
    #pragma unroll
    for (int mi=0;mi<2;mi++)
      a[mi] = *reinterpret_cast<const bf16x8*>(&As[w*32 + mi*16 + lc][ks*32 + g*8]);
    #pragma unroll
    for (int nj=0;nj<8;nj++)
      b[nj] = *reinterpret_cast<const bf16x8*>(&Ws[nj*16 + lc][ks*32 + g*8]);
    #pragma unroll
    for (int mi=0;mi<2;mi++)
      #pragma unroll
      for (int nj=0;nj<8;nj++)
        acc[mi][nj] = mfma16(a[mi], b[nj], acc[mi][nj]);
  }

  float bv[8];
  #pragma unroll
  for (int nj=0;nj<8;nj++) bv[nj] = bias[bn*128 + nj*16 + lc];

  const int c3 = bn >> 4, h = bn & 15;
  if (c3 < 2) {
    unsigned short* dst = (c3 == 0) ? qo : ko;
    const float mul = (c3 == 1) ? 0.12751742f : 1.0f;
    #pragma unroll
    for (int mi=0;mi<2;mi++)
      #pragma unroll
      for (int r=0;r<4;r++) {
        int mrow = bm*128 + w*32 + mi*16 + g*4 + r;
        int bb = mrow >> 10, s = mrow & 1023;
        size_t ob = ((size_t)(bb*H_ + h)*S_ + s)*E_;
        #pragma unroll
        for (int nj=0;nj<4;nj++) {
          int e1 = nj*16 + lc;
          float x1 = acc[mi][nj][r]   + bv[nj];
          float x2 = acc[mi][nj+4][r] + bv[nj+4];
          float cs = ctab[s*64 + e1], sn = stab[s*64 + e1];
          dst[ob + e1]      = f2b((x1*cs - x2*sn) * mul);
          dst[ob + e1 + 64] = f2b((x1*sn + x2*cs) * mul);
        }
      }
  } else {
    __syncthreads();
    #pragma unroll
    for (int mi=0;mi<2;mi++)
      #pragma unroll
      for (int nj=0;nj<8;nj++)
        #pragma unroll
        for (int r=0;r<4;r++)
          As[nj*16 + lc][w*32 + mi*16 + g*4 + r] = f2b(acc[mi][nj][r] + bv[nj]);
    __syncthreads();
    int bb = bm >> 3, sb = (bm & 7) * 128;
    #pragma unroll
    for (int i=0;i<8;i++) {
      int cidx = t + i*256, e = cidx >> 4, sc = cidx & 15;
      *reinterpret_cast<bf16x8*>(&vt[((size_t)(bb*H_ + h)*E_ + e)*S_ + sb + sc*8]) =
          *reinterpret_cast<const bf16x8*>(&As[e][sc*8]);
    }
  }
}

// ---------------- flash attention: 4 waves x 64 q-rows each, KVBLK=32, 32x32 MFMA ----------------
__global__ __launch_bounds__(256, 2) void attn_kernel(
    const unsigned short* __restrict__ qg, const unsigned short* __restrict__ kg,
    const unsigned short* __restrict__ vtg, float* __restrict__ out)
{
  // K tile: [32 kv][128 d], 16B-block XOR-swizzle on low 3 block bits
  // V^T tile: [128 d][32 kv], 16B-block XOR-swizzle on 2 block bits
  __shared__ unsigned short Ks[2][32*128];
  __shared__ unsigned short Vs[2][128*32];
  const int bh = blockIdx.x, qb = blockIdx.y;
  const int t = threadIdx.x, w = t >> 6, l = t & 63;
  const int q32 = l & 31, hi = l >> 5;
  const size_t base = (size_t)bh * (S_*E_);
  const int bb = bh >> 4, h = bh & 15;

  // Q resident: wave w owns rows qb*256 + w*64 + qb2*32 + q32
  bf16x8 qreg[2][8];
  #pragma unroll
  for (int qb2=0;qb2<2;qb2++) {
    const unsigned short* qrow = qg + base + (size_t)(qb*256 + w*64 + qb2*32 + q32)*E_;
    #pragma unroll
    for (int dc=0;dc<8;dc++)
      qreg[qb2][dc] = *reinterpret_cast<const bf16x8*>(qrow + dc*16 + hi*8);
  }

  // pre-swizzled global sources for the linear-dest global_load_lds stage
  const unsigned short* ksrc[2]; const unsigned short* vsrc[2];
  #pragma unroll
  for (int i=0;i<2;i++) {
    int idx = i*256 + t;
    int r = idx >> 4, cb = idx & 15;
    int sb = (cb & 8) | ((cb ^ r) & 7);
    ksrc[i] = kg + base + (size_t)r*E_ + sb*8;
    int rd = idx >> 2, vb = idx & 3;
    int svb = (vb ^ rd) & 3;
    vsrc[i] = vtg + base + (size_t)rd*S_ + svb*8;
  }

  auto stage = [&](int bufi, int tt) {
    #pragma unroll
    for (int i=0;i<2;i++)
      __builtin_amdgcn_global_load_lds(
        (const __attribute__((address_space(1))) void*)(ksrc[i] + (size_t)tt*32*E_),
        (__attribute__((address_space(3))) void*)(&Ks[bufi][(i*256 + w*64)*8]),
        16, 0, 0);
    #pragma unroll
    for (int i=0;i<2;i++)
      __builtin_amdgcn_global_load_lds(
        (const __attribute__((address_space(1))) void*)(vsrc[i] + (size_t)tt*32),
        (__attribute__((address_space(3))) void*)(&Vs[bufi][(i*256 + w*64)*8]),
        16, 0, 0);
  };

  const f32x16 z16 = {0,0,0,0,0,0,0,0,0,0,0,0,0,0,0,0};
  f32x16 accO[8];
  #pragma unroll
  for (int i=0;i<8;i++) accO[i] = z16;
  float m_run[2] = {-1e30f, -1e30f}, lsum[2] = {0.f, 0.f};

  stage(0, 0);
  __syncthreads();

  for (int tt = 0; tt < 32; ++tt) {
    const int cur = tt & 1;
    if (tt < 31) stage(cur ^ 1, tt + 1);

    // S^T = K Q^T for both q-blocks: each K-frag feeds 2 MFMAs
    f32x16 s0 = z16, s1 = z16;
    __builtin_amdgcn_s_setprio(1);
    #pragma unroll
    for (int dc=0; dc<8; dc++) {
      int bi = dc*2 + hi;
      int blk = (bi & 8) | ((bi ^ q32) & 7);
      bf16x8 kf = *reinterpret_cast<const bf16x8*>(&Ks[cur][q32*128 + blk*8]);
      s0 = mfma32(kf, qreg[0][dc], s0);
      s1 = mfma32(kf, qreg[1][dc], s1);
    }
    __builtin_amdgcn_s_setprio(0);

    // online softmax + in-register repack, per q-block (independent chains)
    bf16x8 pu[2][2];
    #pragma unroll
    for (int qb2=0; qb2<2; qb2++) {
      f32x16& sv = qb2 ? s1 : s0;
      float tv[8];
      #pragma unroll
      for (int j=0;j<8;j++) tv[j] = fmaxf(sv[j], sv[j+8]);
      #pragma unroll
      for (int st=4; st>0; st>>=1)
        #pragma unroll
        for (int j=0;j<st;j++) tv[j] = fmaxf(tv[j], tv[j+st]);
      float tmax = fmaxf(tv[0], __shfl_xor(tv[0], 32));

      if (!__all(tmax <= m_run[qb2] + 11.54f)) {   // defer-max, THR=8 ln-units
        float mn = fmaxf(m_run[qb2], tmax);
        float al = __builtin_amdgcn_exp2f(m_run[qb2] - mn);
        m_run[qb2] = mn; lsum[qb2] *= al;
        #pragma unroll
        for (int dc=0;dc<4;dc++)
          #pragma unroll
          for (int j=0;j<16;j++) accO[qb2*4+dc][j] *= al;
      }

      float p[16];
      #pragma unroll
      for (int j=0;j<16;j++) p[j] = __builtin_amdgcn_exp2f(sv[j] - m_run[qb2]);
      float ss[8];
      #pragma unroll
      for (int j=0;j<8;j++) ss[j] = p[j] + p[j+8];
      #pragma unroll
      for (int st=4; st>0; st>>=1)
        #pragma unroll
        for (int j=0;j<st;j++) ss[j] += ss[j+st];
      lsum[qb2] += ss[0];   // cross-half reduce deferred to epilogue

      // P -> bf16 B-operand layout (R2-proven shfl_xor(32) exchange pattern)
      #pragma unroll
      for (int kb=0; kb<2; kb++) {
        unsigned c01 = cvtpk(p[kb*8+0], p[kb*8+1]);
        unsigned c23 = cvtpk(p[kb*8+2], p[kb*8+3]);
        unsigned c45 = cvtpk(p[kb*8+4], p[kb*8+5]);
        unsigned c67 = cvtpk(p[kb*8+6], p[kb*8+7]);
        unsigned ta = hi ? c01 : c45;  ta = __shfl_xor(ta, 32);
        unsigned tb = hi ? c23 : c67;  tb = __shfl_xor(tb, 32);
        union { unsigned u[4]; bf16x8 v; } uu;
        uu.u[0] = hi ? ta : c01;
        uu.u[1] = hi ? tb : c23;
        uu.u[2] = hi ? c45 : ta;
        uu.u[3] = hi ? c67 : tb;
        pu[qb2][kb] = uu.v;
      }
    }

    // O^T += V^T P^T: each V-frag feeds 2 MFMAs
    __builtin_amdgcn_s_setprio(1);
    #pragma unroll
    for (int dc=0; dc<4; dc++)
      #pragma unroll
      for (int kb=0; kb<2; kb++) {
        int vb = ((kb*2 + hi) ^ q32) & 3;
        bf16x8 vf = *reinterpret_cast<const bf16x8*>(&Vs[cur][(dc*32 + q32)*32 + vb*8]);
        accO[dc]   = mfma32(vf, pu[0][kb], accO[dc]);
        accO[4+dc] = mfma32(vf, pu[1][kb], accO[4+dc]);
      }
    __builtin_amdgcn_s_setprio(0);

    __syncthreads();   // drains stage(t+1) + protects buffer swap
  }

  // epilogue
  #pragma unroll
  for (int qb2=0; qb2<2; qb2++) {
    float lt = lsum[qb2] + __shfl_xor(lsum[qb2], 32);
    float inv = 1.0f / lt;
    const int s = qb*256 + w*64 + qb2*32 + q32;
    float* orow = out + ((size_t)(bb*S_ + s)*H_ + h)*E_;
    #pragma unroll
    for (int dc=0;dc<4;dc++)
      #pragma unroll
      for (int rq=0;rq<4;rq++) {
        float4 o4;
        o4.x = accO[qb2*4+dc][rq*4+0]*inv;
        o4.y = accO[qb2*4+dc][rq*4+1]*inv;
        o4.z = accO[qb2*4+dc][rq*4+2]*inv;
        o4.w = accO[qb2*4+dc][rq*4+3]*inv;
        *reinterpret_cast<float4*>(orow + dc*32 + rq*8 + hi*4) = o4;
      }
  }
}

extern "C" void kernel_launch(void* const* d_in, const int* in_sizes, int n_in,
                              void* d_out, int out_size, void* d_ws, size_t ws_size,
                              hipStream_t stream) {
  const float* seq = (const float*)d_in[0];
  const float* wq  = (const float*)d_in[1];
  const float* bq  = (const float*)d_in[2];
  float* out = (float*)d_out;
  char* ws = (char*)d_ws;
  size_t off = 0;
  unsigned short* seqb = (unsigned short*)(ws + off); off += (size_t)M_*E_*2;
  unsigned short* wb   = (unsigned short*)(ws + off); off += (size_t)F_*E_*2;
  float* ctab = (float*)(ws + off); off += (size_t)S_*64*4;
  float* stab = (float*)(ws + off); off += (size_t)S_*64*4;
  unsigned short* qbuf = (unsigned short*)(ws + off); off += (size_t)B_*H_*S_*E_*2;
  unsigned short* kbuf = (unsigned short*)(ws + off); off += (size_t)B_*H_*S_*E_*2;
  unsigned short* vtbuf= (unsigned short*)(ws + off); off += (size_t)B_*H_*S_*E_*2;

  prep_kernel<<<dim3(1024), dim3(256), 0, stream>>>(seq, wq, seqb, wb, ctab, stab);
  qkv_gemm_kernel<<<dim3(64, 48), dim3(256), 0, stream>>>(seqb, wb, bq, ctab, stab, qbuf, kbuf, vtbuf);
  attn_kernel<<<dim3(128, 4), dim3(256), 0, stream>>>(qbuf, kbuf, vtbuf, out);
}